// Round 1
// baseline (170.402 us; speedup 1.0000x reference)
//
#include <hip/hip_runtime.h>

// WordEmbed: out[token, :] = embedding[input_ids[token], :]
// ids: (2,2048) int32 -> 4096 tokens; embedding: (32000,1024) f32; out: (4096,1024) f32
// 1024 floats = 256 float4 per row.
//
// Timing decomposition (rocprof): measured graph = harness fill (79.3us) +
// input-restore copy (81.0us) + this kernel (~9.2us). Only the kernel term is
// ours to optimize. This version raises occupancy 2 -> 8 waves/SIMD
// (2048 blocks x 256 thr, 2 tokens/block) to cover per-wave store-drain
// waitcnt stalls; per-SIMD load MLP is unchanged (invariant under tiling).
//
// Native clang vector type (not HIP_vector_type) so nontemporal builtins accept it.

typedef float vfloat4 __attribute__((ext_vector_type(4)));

#define TOKENS_PER_BLOCK 2

__global__ __launch_bounds__(256) void WordEmbed_7971459302123_kernel(
    const int* __restrict__ ids,
    const vfloat4* __restrict__ emb,   // [32000 * 256] vfloat4
    vfloat4* __restrict__ out)         // [4096 * 256] vfloat4
{
    const int t = threadIdx.x;                          // 0..255 (float4 idx in row)
    const int tok0 = blockIdx.x * TOKENS_PER_BLOCK;

    // Wave-uniform id loads (compiler emits s_load_dwordx2).
    const int id0 = ids[tok0];
    const int id1 = ids[tok0 + 1];

    // Two independent gathered row reads (4KB contiguous each, L3-resident
    // table) -> two NT stores (bypass L2/L3 so the cached embedding stays hot).
    vfloat4 v0 = emb[(size_t)id0 * 256 + t];
    vfloat4 v1 = emb[(size_t)id1 * 256 + t];
    __builtin_nontemporal_store(v0, &out[(size_t)tok0 * 256 + t]);
    __builtin_nontemporal_store(v1, &out[(size_t)(tok0 + 1) * 256 + t]);
}

extern "C" void kernel_launch(void* const* d_in, const int* in_sizes, int n_in,
                              void* d_out, int out_size, void* d_ws, size_t ws_size,
                              hipStream_t stream) {
    const int* ids = (const int*)d_in[0];            // 4096 int32
    const vfloat4* emb = (const vfloat4*)d_in[1];    // 32000*1024 f32
    vfloat4* out = (vfloat4*)d_out;                  // 4096*1024 f32

    const int n_tokens = in_sizes[0];                // 4096
    const int n_blocks = (n_tokens + TOKENS_PER_BLOCK - 1) / TOKENS_PER_BLOCK; // 2048
    WordEmbed_7971459302123_kernel<<<n_blocks, 256, 0, stream>>>(ids, emb, out);
}